// Round 7
// baseline (90.731 us; speedup 1.0000x reference)
//
#include <hip/hip_runtime.h>
#include <math.h>

// SSIM (16,3,512,512) fp32, 11x11 separable Gaussian, VALID -> per-batch mean [16].
//
// Round-7: barrier-free per-wave streaming + in-iteration LDS prefetch.
//  - Each wave owns a 128-output-col strip (2 cols/thread), stages its own
//    rows via global_load_lds; per-wave vmcnt is the only synchronization.
//  - Iteration order: H-pass(row k) -> vmcnt(16) -> prefetch q(row k+1) ->
//    V-pass+SSIM (covers ds_read latency) -> STAGE(row k+LA).
//  - Element-shared H-pass: sq=r^2+d^2 and p=r*d computed once per element,
//    consumed by both columns' taps (124 ops/row vs 154).
//  - 4-channel register ring {r,d,rr+dd,rd} x 2 cols, all indices static.
//  - 255x scaling cancels: C1 = 1e-4, C2 = 9e-4 on [0,1] data.

#define WSZ 11
#define IMG 512
#define OSZ 502
#define NT  256
#define CH_OUT 32
#define NCHUNK 16        // 16*32 >= 502
#define LA 6             // lookahead rows (slots = WSZ = 11)

struct WinArg { float w[WSZ]; };

typedef const __attribute__((address_space(1))) unsigned int* gp_t;
typedef __attribute__((address_space(3))) unsigned int* sp_t;

#define C1V 1.0e-4f
#define C2V 9.0e-4f

__global__ __launch_bounds__(NT, 3) void ssim_pf(
    const float* __restrict__ rawp, const float* __restrict__ dstp,
    float* __restrict__ out, WinArg wa, float inv_n)
{
    // waves 0-2: 11 slots x 80 float4; wave 3: 11 x 64 (laid out at 880*w)
    __shared__ float4 srow[3344];            // 53504 B -> 3 blocks/CU by LDS
    __shared__ float wred[NT / 64];

    const int tid  = threadIdx.x;
    const int lane = tid & 63;
    const int wave = tid >> 6;
    const int chunk = blockIdx.x;
    const int img   = blockIdx.y;

    const int o0    = chunk * CH_OUT;
    const int olim  = min(o0 + CH_OUT, OSZ);
    const int rlast = min(o0 + CH_OUT + WSZ - 2, IMG - 1);
    const int NR    = rlast - o0 + 1;        // 42 (32 for last chunk)

    const bool w3     = (wave == 3);
    const int  nch    = w3 ? 4 : 5;          // DMA chunks per row (wave-uniform)
    const int  slotf4 = w3 ? 64 : 80;        // float4 per slot (wave-uniform)
    float4* region = srow + wave * 880;
    const int  rl     = (w3 && lane > 58) ? 58 : lane;   // read clamp
    const bool active = !(w3 && lane > 58);

    const size_t ibase = (size_t)img * (size_t)(IMG * IMG);
    // lane parity -> channel; (lane>>1) -> col within 32-col chunk
    const float* lane_base = ((lane & 1) ? dstp : rawp) + ibase
                           + (size_t)(wave * 128 + (lane >> 1));

#define STAGE(ROW, SLOT)                                                       \
    {                                                                          \
        const float* _s = lane_base + (size_t)(ROW) * IMG;                     \
        float* _d = (float*)(region + (SLOT) * slotf4);                        \
        _Pragma("unroll")                                                      \
        for (int _c = 0; _c < 5; ++_c) {                                       \
            if (_c < nch)                                                      \
                __builtin_amdgcn_global_load_lds(                              \
                    (gp_t)(const void*)(_s + 32 * _c),                         \
                    (sp_t)(void*)(_d + 64 * _c), 4, 0, 0);                     \
        }                                                                      \
    }

    float hs[WSZ][4][2];                     // ring: [slot][{r,d,rr+dd,rd}][col]
    float4 q[6];                             // current row window
    float acc = 0.0f;

    // ---- prologue: rows 0..LA-1 in flight; load q <- row 0 ----
#pragma unroll
    for (int r = 0; r < LA; ++r) STAGE(o0 + r, r)
    asm volatile("s_waitcnt vmcnt(16)" ::: "memory");   // row 0 landed
    {
        const float4* rp = region + 0 * slotf4 + rl;
#pragma unroll
        for (int j = 0; j < 6; ++j) q[j] = rp[j];
    }

#pragma unroll 1
    for (int rr = 0; rr < NR; rr += WSZ) {
#pragma unroll
        for (int k = 0; k < WSZ; ++k) {
            const int klin = rr + k;
            if (klin < NR) {                 // block-uniform
                // ---- H-pass on q (row klin), element-shared both cols ----
                float s1a = 0.f, s2a = 0.f, s3a = 0.f, s4a = 0.f;
                float s1b = 0.f, s2b = 0.f, s3b = 0.f, s4b = 0.f;
#pragma unroll
                for (int e = 0; e < 12; ++e) {
                    const float r = (e & 1) ? q[e >> 1].z : q[e >> 1].x;
                    const float d = (e & 1) ? q[e >> 1].w : q[e >> 1].y;
                    const float sq = fmaf(d, d, r * r);
                    const float p  = r * d;
                    if (e < 11) {            // col a tap e
                        const float w_ = wa.w[e];
                        s1a = fmaf(w_, r, s1a);
                        s2a = fmaf(w_, d, s2a);
                        s3a = fmaf(w_, sq, s3a);
                        s4a = fmaf(w_, p,  s4a);
                    }
                    if (e >= 1) {            // col b tap e-1
                        const float w_ = wa.w[e - 1];
                        s1b = fmaf(w_, r, s1b);
                        s2b = fmaf(w_, d, s2b);
                        s3b = fmaf(w_, sq, s3b);
                        s4b = fmaf(w_, p,  s4b);
                    }
                }
                hs[k][0][0] = s1a; hs[k][1][0] = s2a; hs[k][2][0] = s3a; hs[k][3][0] = s4a;
                hs[k][0][1] = s1b; hs[k][1][1] = s2b; hs[k][2][1] = s3b; hs[k][3][1] = s4b;

                // ---- prefetch q <- row klin+1 (latency hidden by V-pass) ----
                asm volatile("s_waitcnt vmcnt(16)" ::: "memory");  // row klin+1 landed
                {
                    const float4* rp = region + ((k + 1) % WSZ) * slotf4 + rl;
#pragma unroll
                    for (int j = 0; j < 6; ++j) q[j] = rp[j];
                }

                // ---- V-pass + SSIM ----
                const int o = o0 + klin - (WSZ - 1);
                if (klin >= WSZ - 1 && o < olim && active) {
                    float m1a = 0.f, m2a = 0.f, m3a = 0.f, m4a = 0.f;
                    float m1b = 0.f, m2b = 0.f, m3b = 0.f, m4b = 0.f;
#pragma unroll
                    for (int i = 0; i < WSZ; ++i) {
                        const int s = (k + 1 + i) % WSZ;   // static after unroll
                        const float wi = wa.w[i];
                        m1a = fmaf(wi, hs[s][0][0], m1a);
                        m2a = fmaf(wi, hs[s][1][0], m2a);
                        m3a = fmaf(wi, hs[s][2][0], m3a);
                        m4a = fmaf(wi, hs[s][3][0], m4a);
                        m1b = fmaf(wi, hs[s][0][1], m1b);
                        m2b = fmaf(wi, hs[s][1][1], m2b);
                        m3b = fmaf(wi, hs[s][2][1], m3b);
                        m4b = fmaf(wi, hs[s][3][1], m4b);
                    }
                    {
                        const float q1 = m1a * m1a, q2 = m2a * m2a, mm = m1a * m2a;
                        const float num = (2.f * mm + C1V) * (2.f * (m4a - mm) + C2V);
                        const float den = (q1 + q2 + C1V) * (((m3a - q1) - q2) + C2V);
                        acc += num * __builtin_amdgcn_rcpf(den);
                    }
                    {
                        const float q1 = m1b * m1b, q2 = m2b * m2b, mm = m1b * m2b;
                        const float num = (2.f * mm + C1V) * (2.f * (m4b - mm) + C2V);
                        const float den = (q1 + q2 + C1V) * (((m3b - q1) - q2) + C2V);
                        acc += num * __builtin_amdgcn_rcpf(den);
                    }
                }

                // ---- stage row klin+LA (clamped tail keeps vmcnt exact) ----
                {
                    int rs = klin + LA; if (rs > NR - 1) rs = NR - 1;
                    STAGE(o0 + rs, (k + LA) % WSZ)
                }
            }
        }
    }
#undef STAGE

    // ---- block reduction -> one atomicAdd per block ----
#pragma unroll
    for (int off = 32; off > 0; off >>= 1) acc += __shfl_down(acc, off, 64);
    if (lane == 0) wred[wave] = acc;
    __syncthreads();
    if (tid == 0) {
        const float tot = (wred[0] + wred[1]) + (wred[2] + wred[3]);
        atomicAdd(out + img / 3, tot * inv_n);
    }
}

extern "C" void kernel_launch(void* const* d_in, const int* in_sizes, int n_in,
                              void* d_out, int out_size, void* d_ws, size_t ws_size,
                              hipStream_t stream) {
    const float* raw = (const float*)d_in[0];
    const float* dst = (const float*)d_in[1];
    float* out = (float*)d_out;

    hipMemsetAsync(out, 0, (size_t)out_size * sizeof(float), stream);

    WinArg wa;
    double g[WSZ], s = 0.0;
    for (int i = 0; i < WSZ; ++i) {
        double ax = (double)i - (double)(WSZ - 1) / 2.0;
        g[i] = exp(-(ax * ax) / (2.0 * 1.5 * 1.5));
        s += g[i];
    }
    for (int i = 0; i < WSZ; ++i) wa.w[i] = (float)(g[i] / s);

    const float inv_n = (float)(1.0 / (3.0 * (double)OSZ * (double)OSZ));

    dim3 grid(NCHUNK, 48);
    ssim_pf<<<grid, NT, 0, stream>>>(raw, dst, out, wa, inv_n);
}

// Round 8
// 87.519 us; speedup vs baseline: 1.0367x; 1.0367x over previous
//
#include <hip/hip_runtime.h>
#include <math.h>

// SSIM (16,3,512,512) fp32, 11x11 separable Gaussian, VALID -> per-batch mean [16].
//
// Round-8: parity-split wave pairs, 1 output column per thread.
//  - Block = 256 threads = 4 waves = 2 wave-pairs; each pair owns one 128-col
//    strip. Within a pair, wave parity P handles cols 2l+P; both waves read
//    the SAME float4 window q[l..l+5] of the shared strip; extraction pattern
//    (elements 0..10 vs 1..11) is wave-uniform and fully static.
//  - Register ring halves to 11x4 = 44 floats -> ~95 VGPRs -> 4-5 waves/SIMD.
//  - Staging deduplicated: P=0 stages chunks {0,2,4} (vmcnt 18), P=1 stages
//    {1,3} (vmcnt 12); strip 3 has 4 chunks, 2 each (vmcnt 12). One s_barrier
//    per row syncs the pair; sched_barrier(0) pins ds_reads after it.
//  - LDS = 2 strips x 11 slots x 80 float4 = 28160 B -> 5 blocks/CU.
//  - 255x scaling cancels: C1 = 1e-4, C2 = 9e-4 on [0,1] data.

#define WSZ 11
#define IMG 512
#define OSZ 502
#define NT  256
#define CH_OUT 32
#define NCHUNK 16        // 16*32 >= 502
#define LA 6             // lookahead rows (ring slots = WSZ = 11)
#define SLOTF4 80        // float4 per slot (160 cols, channel-interleaved)

struct WinArg { float w[WSZ]; };

typedef const __attribute__((address_space(1))) unsigned int* gp_t;
typedef __attribute__((address_space(3))) unsigned int* sp_t;

#define C1V 1.0e-4f
#define C2V 9.0e-4f

__global__ __launch_bounds__(NT, 4) void ssim_pair(
    const float* __restrict__ rawp, const float* __restrict__ dstp,
    float* __restrict__ out, WinArg wa, float inv_n)
{
    __shared__ float4 srow[2 * WSZ * SLOTF4];   // 28160 B
    __shared__ float wred[NT / 64];

    const int tid  = threadIdx.x;
    const int lane = tid & 63;
    const int wave = tid >> 6;
    const int sp    = blockIdx.x & 1;           // strip pair: {0,1} or {2,3}
    const int chunk = blockIdx.x >> 1;
    const int img   = blockIdx.y;

    const int sl = wave >> 1;                   // strip slot in LDS (0..1)
    const int S  = sp * 2 + sl;                 // global strip (0..3)
    const int P  = wave & 1;                    // column parity

    const int o0    = chunk * CH_OUT;
    const int olim  = min(o0 + CH_OUT, OSZ);
    const int rlast = min(o0 + CH_OUT + WSZ - 2, IMG - 1);
    const int NR    = rlast - o0 + 1;           // 42 (32 for last chunk)

    const bool s3w  = (S == 3);                 // strip 3: 128 cols, 4 chunks
    const int  nch  = s3w ? 4 : 5;
    const bool big  = (!s3w) && (P == 0);       // stages 3 chunks (else 2)
    float4* region  = srow + sl * (WSZ * SLOTF4);
    const int  rl     = (s3w && lane > 58) ? 58 : lane;  // read clamp
    const bool active = !(s3w && lane > 58);    // col = 128S+2l+P <= 501

    const size_t ibase = (size_t)img * (size_t)(IMG * IMG);
    // staging: lane parity -> channel, (lane>>1) -> col within 32-col chunk
    const float* lane_base = ((lane & 1) ? dstp : rawp) + ibase
                           + (size_t)(S * 128 + (lane >> 1));

    // each wave stages chunks with (_c & 1) == P  (disjoint, union = all)
#define STAGE(ROW, SLOT)                                                       \
    {                                                                          \
        const float* _s = lane_base + (size_t)(ROW) * IMG;                     \
        float* _d = (float*)(region + (SLOT) * SLOTF4);                        \
        _Pragma("unroll")                                                      \
        for (int _c = 0; _c < 5; ++_c) {                                       \
            if (_c < nch && (_c & 1) == P)                                     \
                __builtin_amdgcn_global_load_lds(                              \
                    (gp_t)(const void*)(_s + 32 * _c),                         \
                    (sp_t)(void*)(_d + 64 * _c), 4, 0, 0);                     \
        }                                                                      \
    }

    float hs[WSZ][4];                           // ring: [slot][{r,d,rr+dd,rd}]
    float acc = 0.0f;

    // prologue: rows 0..LA-1 in flight
#pragma unroll
    for (int r = 0; r < LA; ++r) STAGE(o0 + r, r)

#pragma unroll 1
    for (int rr = 0; rr < NR; rr += WSZ) {
#pragma unroll
        for (int k = 0; k < WSZ; ++k) {
            const int klin = rr + k;
            if (klin < NR) {                    // block-uniform
                // stage row klin+LA (clamped tail restage lands in dead slot)
                {
                    int rs = klin + LA; if (rs > NR - 1) rs = NR - 1;
                    STAGE(o0 + rs, (k + LA) % WSZ)
                }
                // per-wave wait for own oldest row, then pair-sync barrier
                if (big) asm volatile("s_waitcnt vmcnt(18)" ::: "memory");
                else     asm volatile("s_waitcnt vmcnt(12)" ::: "memory");
                __builtin_amdgcn_s_barrier();
                __builtin_amdgcn_sched_barrier(0);

                float4 q[6];
                {
                    const float4* rp = region + k * SLOTF4 + rl;
#pragma unroll
                    for (int j = 0; j < 6; ++j) q[j] = rp[j];
                }

                // ---- H-pass: one column, elements P..P+10 (static) ----
                float s1, s2, s3, s4;
#define HPASS(PP)                                                              \
                {                                                              \
                    float a1 = 0.f, a2 = 0.f, a3 = 0.f, a4 = 0.f;              \
                    _Pragma("unroll")                                          \
                    for (int j = 0; j < WSZ; ++j) {                            \
                        const int e = (PP) + j;                                \
                        const float wj = wa.w[j];                              \
                        const float r = (e & 1) ? q[e >> 1].z : q[e >> 1].x;   \
                        const float d = (e & 1) ? q[e >> 1].w : q[e >> 1].y;   \
                        a1 = fmaf(wj, r, a1);                                  \
                        a2 = fmaf(wj, d, a2);                                  \
                        a3 = fmaf(wj, fmaf(d, d, r * r), a3);                  \
                        a4 = fmaf(wj, r * d, a4);                              \
                    }                                                          \
                    s1 = a1; s2 = a2; s3 = a3; s4 = a4;                        \
                }
                if (P == 0) { HPASS(0) } else { HPASS(1) }
#undef HPASS
                hs[k][0] = s1; hs[k][1] = s2; hs[k][2] = s3; hs[k][3] = s4;

                // ---- V-pass + SSIM ----
                const int o = o0 + klin - (WSZ - 1);
                if (klin >= WSZ - 1 && o < olim && active) {
                    float m1 = 0.f, m2 = 0.f, m3 = 0.f, m4 = 0.f;
#pragma unroll
                    for (int i = 0; i < WSZ; ++i) {
                        const int s = (k + 1 + i) % WSZ;   // static after unroll
                        const float wi = wa.w[i];
                        m1 = fmaf(wi, hs[s][0], m1);
                        m2 = fmaf(wi, hs[s][1], m2);
                        m3 = fmaf(wi, hs[s][2], m3);
                        m4 = fmaf(wi, hs[s][3], m4);
                    }
                    const float q1 = m1 * m1, q2 = m2 * m2, mm = m1 * m2;
                    const float num = (2.f * mm + C1V) * (2.f * (m4 - mm) + C2V);
                    const float den = (q1 + q2 + C1V) * (((m3 - q1) - q2) + C2V);
                    acc += num * __builtin_amdgcn_rcpf(den);
                }
            }
        }
    }
#undef STAGE

    // ---- block reduction -> one atomicAdd per block ----
#pragma unroll
    for (int off = 32; off > 0; off >>= 1) acc += __shfl_down(acc, off, 64);
    if (lane == 0) wred[wave] = acc;
    __syncthreads();
    if (tid == 0) {
        const float tot = (wred[0] + wred[1]) + (wred[2] + wred[3]);
        atomicAdd(out + img / 3, tot * inv_n);
    }
}

extern "C" void kernel_launch(void* const* d_in, const int* in_sizes, int n_in,
                              void* d_out, int out_size, void* d_ws, size_t ws_size,
                              hipStream_t stream) {
    const float* raw = (const float*)d_in[0];
    const float* dst = (const float*)d_in[1];
    float* out = (float*)d_out;

    hipMemsetAsync(out, 0, (size_t)out_size * sizeof(float), stream);

    WinArg wa;
    double g[WSZ], s = 0.0;
    for (int i = 0; i < WSZ; ++i) {
        double ax = (double)i - (double)(WSZ - 1) / 2.0;
        g[i] = exp(-(ax * ax) / (2.0 * 1.5 * 1.5));
        s += g[i];
    }
    for (int i = 0; i < WSZ; ++i) wa.w[i] = (float)(g[i] / s);

    const float inv_n = (float)(1.0 / (3.0 * (double)OSZ * (double)OSZ));

    dim3 grid(2 * NCHUNK, 48);
    ssim_pair<<<grid, NT, 0, stream>>>(raw, dst, out, wa, inv_n);
}